// Round 1
// baseline (4227.383 us; speedup 1.0000x reference)
//
#include <hip/hip_runtime.h>
#include <math.h>

#define KB       8            // blocks (one per XCD)
#define NTHREADS 256
#define HID      4096
#define HB       (HID / KB)   // 512 neurons per block
#define TT       1000
#define PP       16

#define BETA 0.9f
#define THRV 0.5f
#define DTV  0.005f

// ws layout: [0,4096) counters[1000] int ; [4096, 4096+2*KB*16*4) slot ring f32
__global__ void zero_kernel(int* counters, float* out) {
    int i = blockIdx.x * blockDim.x + threadIdx.x;
    if (i < TT) counters[i] = 0;
    if (i < 2 * TT) out[i] = 0.f;
}

__global__ __launch_bounds__(NTHREADS, 1)
void snn_kernel(const float* __restrict__ x,
                const float* __restrict__ noise,
                const float* __restrict__ Win,
                const float* __restrict__ Wout,
                const float* __restrict__ pin,
                const float* __restrict__ pout,
                const float* __restrict__ lvec,
                const float* __restrict__ stdv,
                float* __restrict__ out,
                int* __restrict__ counters,
                float* __restrict__ slots)
{
    const int b    = blockIdx.x;
    const int tid  = threadIdx.x;
    const int wave = tid >> 6;
    const int lane = tid & 63;
    const int h0   = b * HB + tid * 2;   // two consecutive neurons per thread
    const int h1   = h0 + 1;

    __shared__ float part[2][4][20];     // [parity][wave][18 values, padded]
    __shared__ float ubuf[4][16];        // per-wave u broadcast area

    // ---------------- parameter load (once) ----------------
    float lv[PP];
    #pragma unroll
    for (int p = 0; p < PP; p += 4) {
        float4 t4 = *(const float4*)&lvec[p];
        lv[p] = t4.x; lv[p+1] = t4.y; lv[p+2] = t4.z; lv[p+3] = t4.w;
    }
    float pl0[PP], pl1[PP], po0[PP], po1[PP];
    #pragma unroll
    for (int p = 0; p < PP; p += 4) {
        float4 a = *(const float4*)&pin[h0*PP + p];
        float4 c = *(const float4*)&pin[h1*PP + p];
        pl0[p]   = a.x*lv[p];   pl0[p+1] = a.y*lv[p+1];
        pl0[p+2] = a.z*lv[p+2]; pl0[p+3] = a.w*lv[p+3];
        pl1[p]   = c.x*lv[p];   pl1[p+1] = c.y*lv[p+1];
        pl1[p+2] = c.z*lv[p+2]; pl1[p+3] = c.w*lv[p+3];
        float4 e = *(const float4*)&pout[h0*PP + p];
        float4 f = *(const float4*)&pout[h1*PP + p];
        po0[p]   = e.x; po0[p+1] = e.y; po0[p+2] = e.z; po0[p+3] = e.w;
        po1[p]   = f.x; po1[p+1] = f.y; po1[p+2] = f.z; po1[p+3] = f.w;
    }
    const float2* win2 = (const float2*)Win;          // Win row h = float2 idx h*3..h*3+2
    float2 wa0 = win2[h0*3], wb0 = win2[h0*3+1], wc0 = win2[h0*3+2];
    float2 wa1 = win2[h1*3], wb1 = win2[h1*3+1], wc1 = win2[h1*3+2];
    float2 wo_a = *(const float2*)&Wout[h0];          // Wout[0][h0..h1]
    float2 wo_b = *(const float2*)&Wout[HID + h0];    // Wout[1][h0..h1]

    float2 sd = *(const float2*)&stdv[h0];
    float sig0 = 1.f / (1.f + expf(-sd.x));
    float sig1 = 1.f / (1.f + expf(-sd.y));
    float tau0 = sig0 * 0.03f + 0.02f;
    float tau1 = sig1 * 0.03f + 0.02f;
    float dd0  = expf(-DTV / tau0);
    float dd1  = expf(-DTV / tau1);
    float sg0  = DTV / (tau0 * 0.002f);
    float sg1  = DTV / (tau1 * 0.002f);
    const float DECAY_R = expf(-2.5f);

    // ---------------- state ----------------
    float mem0 = 0.f, mem1 = 0.f, r0 = 0.f, r1 = 0.f, s0 = 0.f, s1 = 0.f;

    const float2* x2 = (const float2*)x;
    float2 nz = *(const float2*)&noise[h0];           // t = 0
    float2 xa = x2[0], xb = x2[1], xc = x2[2];

    for (int t = 0; t < TT; ++t) {
        // prefetch next step's inputs (overlaps sync below)
        const int tn = (t + 1 < TT) ? t + 1 : t;
        float2 nz_n = *(const float2*)&noise[tn * HID + h0];
        float2 xa_n = x2[tn*3], xb_n = x2[tn*3+1], xc_n = x2[tn*3+2];

        float uu[16];
        if (t > 0) {
            const int par = t & 1;
            // ---- phase A: 18-value block reduction of r_{t-1} products ----
            float pa[18];
            #pragma unroll
            for (int p = 0; p < PP; ++p) pa[p] = po0[p]*r0 + po1[p]*r1;
            pa[16] = wo_a.x*r0 + wo_a.y*r1;
            pa[17] = wo_b.x*r0 + wo_b.y*r1;
            #pragma unroll
            for (int m = 1; m < 64; m <<= 1) {
                #pragma unroll
                for (int j = 0; j < 18; ++j) pa[j] += __shfl_xor(pa[j], m, 64);
            }
            if (lane == 0) {
                float* pw = &part[par][wave][0];
                *(float4*)&pw[0]  = make_float4(pa[0],pa[1],pa[2],pa[3]);
                *(float4*)&pw[4]  = make_float4(pa[4],pa[5],pa[6],pa[7]);
                *(float4*)&pw[8]  = make_float4(pa[8],pa[9],pa[10],pa[11]);
                *(float4*)&pw[12] = make_float4(pa[12],pa[13],pa[14],pa[15]);
                *(float2*)&pw[16] = make_float2(pa[16],pa[17]);
            }
            __syncthreads();
            if (tid == 0) {
                float tj[18];
                #pragma unroll
                for (int j = 0; j < 18; ++j)
                    tj[j] = (part[par][0][j] + part[par][1][j])
                          + (part[par][2][j] + part[par][3][j]);
                float* slot = slots + (size_t)(par * KB + b) * PP;
                #pragma unroll
                for (int p = 0; p < PP; ++p)
                    __hip_atomic_store(&slot[p], tj[p], __ATOMIC_RELAXED,
                                       __HIP_MEMORY_SCOPE_AGENT);
                atomicAdd(&out[(t-1)*2 + 0], tj[16]);   // y[t-1] partial
                atomicAdd(&out[(t-1)*2 + 1], tj[17]);
                __hip_atomic_fetch_add(&counters[t], 1, __ATOMIC_RELEASE,
                                       __HIP_MEMORY_SCOPE_AGENT);
            }
            // ---- all waves: wait for all blocks, combine slots (fixed tree) ----
            const int* cptr = &counters[t];
            int spin = 0;
            while (__hip_atomic_load(cptr, __ATOMIC_RELAXED,
                                     __HIP_MEMORY_SCOPE_AGENT) < KB) {
                if (++spin > 100000) break;  // failsafe against protocol bugs
            }
            __builtin_amdgcn_fence(__ATOMIC_ACQUIRE, "agent");
            const float* sl = slots + (size_t)par * KB * PP;
            const int pidx = lane & 15, kidx = lane >> 4;
            float sa = __hip_atomic_load(&sl[kidx*PP + pidx], __ATOMIC_RELAXED,
                                         __HIP_MEMORY_SCOPE_AGENT);
            float sb = __hip_atomic_load(&sl[(kidx+4)*PP + pidx], __ATOMIC_RELAXED,
                                         __HIP_MEMORY_SCOPE_AGENT);
            float ss = sa + sb;
            ss += __shfl_xor(ss, 16, 64);
            ss += __shfl_xor(ss, 32, 64);      // lane holds u[lane&15]
            if (lane < 16) ubuf[wave][lane] = ss;
            float4 u0 = *(const float4*)&ubuf[wave][0];
            float4 u1 = *(const float4*)&ubuf[wave][4];
            float4 u2 = *(const float4*)&ubuf[wave][8];
            float4 u3 = *(const float4*)&ubuf[wave][12];
            uu[0]=u0.x; uu[1]=u0.y; uu[2]=u0.z; uu[3]=u0.w;
            uu[4]=u1.x; uu[5]=u1.y; uu[6]=u1.z; uu[7]=u1.w;
            uu[8]=u2.x; uu[9]=u2.y; uu[10]=u2.z; uu[11]=u2.w;
            uu[12]=u3.x; uu[13]=u3.y; uu[14]=u3.z; uu[15]=u3.w;
        } else {
            #pragma unroll
            for (int p = 0; p < 16; ++p) uu[p] = 0.f;
        }

        // ---- phase E: per-neuron update ----
        float rec0 = 0.f, rec1 = 0.f;
        #pragma unroll
        for (int p = 0; p < PP; ++p) { rec0 += pl0[p]*uu[p]; rec1 += pl1[p]*uu[p]; }
        float xw0 = wa0.x*xa.x + wa0.y*xa.y + wb0.x*xb.x + wb0.y*xb.y
                  + wc0.x*xc.x + wc0.y*xc.y;
        float xw1 = wa1.x*xa.x + wa1.y*xa.y + wb1.x*xb.x + wb1.y*xb.y
                  + wc1.x*xc.x + wc1.y*xc.y;
        float I0 = (xw0 + rec0) + nz.x / 10.0f;
        float I1 = (xw1 + rec1) + nz.y / 10.0f;

        float rst0 = (mem0 - THRV > 0.f) ? THRV : 0.f;   // reset from incoming mem
        float rst1 = (mem1 - THRV > 0.f) ? THRV : 0.f;
        mem0 = BETA*mem0 + I0 - rst0;
        mem1 = BETA*mem1 + I1 - rst1;
        float spk0 = (mem0 - THRV > 0.f) ? 1.f : 0.f;
        float spk1 = (mem1 - THRV > 0.f) ? 1.f : 0.f;
        s0 = s0*DECAY_R + sg0*spk0;
        s1 = s1*DECAY_R + sg1*spk1;
        r0 = dd0*r0 + DTV*s0;
        r1 = dd1*r1 + DTV*s1;

        nz = nz_n; xa = xa_n; xb = xb_n; xc = xc_n;
    }

    // ---- final y[T-1] from r_{T-1} (no cross-block sync needed) ----
    {
        float ya = wo_a.x*r0 + wo_a.y*r1;
        float yb = wo_b.x*r0 + wo_b.y*r1;
        #pragma unroll
        for (int m = 1; m < 64; m <<= 1) {
            ya += __shfl_xor(ya, m, 64);
            yb += __shfl_xor(yb, m, 64);
        }
        if (lane == 0) {
            atomicAdd(&out[(TT-1)*2 + 0], ya);
            atomicAdd(&out[(TT-1)*2 + 1], yb);
        }
    }
}

extern "C" void kernel_launch(void* const* d_in, const int* in_sizes, int n_in,
                              void* d_out, int out_size, void* d_ws, size_t ws_size,
                              hipStream_t stream)
{
    const float* x     = (const float*)d_in[0];
    const float* noise = (const float*)d_in[1];
    const float* Win   = (const float*)d_in[2];
    const float* Wout  = (const float*)d_in[3];
    const float* pin   = (const float*)d_in[4];
    const float* pout  = (const float*)d_in[5];
    const float* l     = (const float*)d_in[6];
    const float* stdv  = (const float*)d_in[7];
    float* out    = (float*)d_out;
    int*   counters = (int*)d_ws;
    float* slots    = (float*)((char*)d_ws + 4096);

    hipLaunchKernelGGL(zero_kernel, dim3(8), dim3(256), 0, stream, counters, out);
    hipLaunchKernelGGL(snn_kernel, dim3(KB), dim3(NTHREADS), 0, stream,
                       x, noise, Win, Wout, pin, pout, l, stdv,
                       out, counters, slots);
}